// Round 15
// baseline (1309.874 us; speedup 1.0000x reference)
//
#include <hip/hip_runtime.h>
#include <hip/hip_bf16.h>
#include <stdint.h>

#define B_TOK 8192
#define DD_IN 1024
#define D_HID 4096
#define D_OUT 1024
#define N_EXP 8
#define NT    (N_EXP * D_HID)   // 32768: fused hidden width = GEMM2 K
#define SPLITK 4
#define KS    (NT / SPLITK)     // 8192 k per split block

typedef __attribute__((ext_vector_type(8))) __bf16 bf16x8;
typedef __attribute__((ext_vector_type(4))) float f32x4;

// ------ fused gate+cvt: gate = softmax(x@Wg+bg); xb = bf16(x). 1 wave/row --
__global__ void gate_cvt_kernel(const float* __restrict__ x,
                                const float* __restrict__ Wg,
                                const float* __restrict__ bg,
                                float* __restrict__ gate,
                                __bf16* __restrict__ xb) {
    int wave = threadIdx.x >> 6;
    int lane = threadIdx.x & 63;
    int row  = blockIdx.x * 4 + wave;
    if (row >= B_TOK) return;
    const float* xr = x + (size_t)row * DD_IN;
    __bf16* xbr = xb + (size_t)row * DD_IN;
    float acc[N_EXP];
#pragma unroll
    for (int e = 0; e < N_EXP; ++e) acc[e] = 0.f;
#pragma unroll
    for (int c = 0; c < 4; ++c) {
        int k = (c * 64 + lane) * 4;
        float4 v = *(const float4*)&xr[k];
        __bf16 b0 = (__bf16)v.x, b1 = (__bf16)v.y, b2 = (__bf16)v.z, b3 = (__bf16)v.w;
        ushort4 u;
        u.x = *(unsigned short*)&b0; u.y = *(unsigned short*)&b1;
        u.z = *(unsigned short*)&b2; u.w = *(unsigned short*)&b3;
        *(ushort4*)&xbr[k] = u;
        const float* wg0 = Wg + (size_t)k * N_EXP;
#pragma unroll
        for (int e = 0; e < N_EXP; ++e)
            acc[e] += v.x * wg0[e] + v.y * wg0[N_EXP + e] +
                      v.z * wg0[2 * N_EXP + e] + v.w * wg0[3 * N_EXP + e];
    }
#pragma unroll
    for (int e = 0; e < N_EXP; ++e) {
        float v = acc[e];
        for (int off = 32; off; off >>= 1) v += __shfl_xor(v, off);
        acc[e] = v + bg[e];
    }
    float m = acc[0];
#pragma unroll
    for (int e = 1; e < N_EXP; ++e) m = fmaxf(m, acc[e]);
    float s = 0.f;
#pragma unroll
    for (int e = 0; e < N_EXP; ++e) { acc[e] = expf(acc[e] - m); s += acc[e]; }
    float inv = 1.f / s;
    if (lane < N_EXP) gate[(size_t)row * N_EXP + lane] = acc[lane] * inv;
}

// ---- wide transpose+convert: out[c*ldo + e*eStride + r] = bf16(in[e][r][c])
__global__ __launch_bounds__(256)
void transpose_cvt64(const float* __restrict__ in,
                     __bf16* __restrict__ out, int R, int C,
                     long ldo, long eStride) {
    __shared__ __bf16 tile[64 * 66];
    const float* inp = in + (size_t)blockIdx.z * R * C;
    __bf16* outp = out + (size_t)blockIdx.z * eStride;
    const int c0 = blockIdx.x * 64, r0 = blockIdx.y * 64;
    const int t = threadIdx.x;
    const int lr = t >> 4;
    const int lc = (t & 15) * 4;
#pragma unroll
    for (int p = 0; p < 4; ++p) {
        int r = p * 16 + lr;
        float4 v = *(const float4*)&inp[(size_t)(r0 + r) * C + c0 + lc];
        ushort2 u01, u23;
        __bf16 b0 = (__bf16)v.x, b1 = (__bf16)v.y, b2 = (__bf16)v.z, b3 = (__bf16)v.w;
        u01.x = *(unsigned short*)&b0; u01.y = *(unsigned short*)&b1;
        u23.x = *(unsigned short*)&b2; u23.y = *(unsigned short*)&b3;
        *(ushort2*)&tile[r * 66 + lc]     = u01;
        *(ushort2*)&tile[r * 66 + lc + 2] = u23;
    }
    __syncthreads();
#pragma unroll
    for (int p = 0; p < 2; ++p) {
        int item = p * 256 + t;
        int cc = item >> 3;
        int rb = (item & 7) * 8;
        bf16x8 v;
#pragma unroll
        for (int k = 0; k < 8; ++k) v[k] = tile[(rb + k) * 66 + cc];
        *(bf16x8*)&outp[(size_t)(c0 + cc) * ldo + r0 + rb] = v;
    }
}

// =========================== shared GEMM helpers ===========================
__device__ __forceinline__ void stage_half(const __bf16* __restrict__ gsrc, long ld,
                                           __bf16* ldsbase, int hf, long k0, int t) {
#pragma unroll
    for (int i = 0; i < 2; ++i) {
        int g = i * 512 + t;
        int rl = g >> 3, sl = g & 7;
        int r = hf * 128 + rl;
        const __bf16* src = gsrc + (size_t)r * ld + k0 + ((sl ^ (r & 7)) << 3);
        __builtin_amdgcn_global_load_lds(
            (const __attribute__((address_space(1))) void*)src,
            (__attribute__((address_space(3))) void*)(ldsbase + hf * 8192 + g * 8),
            16, 0, 0);
    }
}

__device__ __forceinline__ bf16x8 ldfrag(const __bf16* buf, int rbase, int l, int ks) {
    int r = rbase + (l & 15);
    int k = ks * 32 + ((l >> 4) << 3);
    return *(const bf16x8*)(buf + r * 64 + (k ^ ((r & 7) << 3)));
}

#define WAIT_LGKM do { asm volatile("s_waitcnt lgkmcnt(0)" ::: "memory"); \
    __builtin_amdgcn_sched_barrier(0); } while (0)
#define BAR __builtin_amdgcn_s_barrier()
#define VMC6 do { asm volatile("s_waitcnt vmcnt(6)" ::: "memory"); \
    __builtin_amdgcn_sched_barrier(0); } while (0)
#define VMC0 do { asm volatile("s_waitcnt vmcnt(0)" ::: "memory"); \
    __builtin_amdgcn_sched_barrier(0); } while (0)

#define RD_A(bufp, mb) do { \
    _Pragma("unroll") for (int mm = 0; mm < 4; ++mm) \
    _Pragma("unroll") for (int ks = 0; ks < 2; ++ks) \
        af[mm * 2 + ks] = ldfrag((bufp), wr * 128 + ((mb) + mm) * 16, l, ks); \
} while (0)
#define RD_B01(bufp) do { \
    _Pragma("unroll") for (int nn = 0; nn < 2; ++nn) \
    _Pragma("unroll") for (int ks = 0; ks < 2; ++ks) \
        bq[nn * 2 + ks] = ldfrag((bufp), wc * 64 + nn * 16, l, ks); \
} while (0)
#define RD_B23(bufp) do { \
    _Pragma("unroll") for (int nn = 2; nn < 4; ++nn) \
    _Pragma("unroll") for (int ks = 0; ks < 2; ++ks) \
        bq[nn * 2 + ks] = ldfrag((bufp), wc * 64 + nn * 16, l, ks); \
} while (0)
#define QMFMA(mb, nb) do { \
    __builtin_amdgcn_s_setprio(1); \
    _Pragma("unroll") for (int mm = 0; mm < 4; ++mm) \
    _Pragma("unroll") for (int nn = 0; nn < 2; ++nn) \
    _Pragma("unroll") for (int ks = 0; ks < 2; ++ks) \
        acc[(mb) + mm][(nb) + nn] = __builtin_amdgcn_mfma_f32_16x16x32_bf16( \
            af[mm * 2 + ks], bq[((nb) + nn) * 2 + ks], acc[(mb) + mm][(nb) + nn], 0, 0, 0); \
    __builtin_amdgcn_s_setprio(0); \
} while (0)

// ====== GEMM1 persistent: 16 col-groups x (rows/256); 8 tiles/block =======
// Flat K-step sequence s in [0,128): tile = s>>4, k = (s&15)*64. The vmcnt(6)
// ledger is continuous across tile boundaries (next tile's stages fill the
// slots); only the global last iteration drains to vmcnt(0).
__global__ __launch_bounds__(512, 2)
void gemm1p(const __bf16* __restrict__ A, long lda,
            const __bf16* __restrict__ Bt, long ldb,
            const float* __restrict__ bias, const float* __restrict__ gate,
            __bf16* __restrict__ outH) {
    __shared__ __bf16 lds[65536];
    const int t = threadIdx.x;
    const int w = t >> 6, l = t & 63;
    const int wr = w >> 2, wc = w & 3;

    // bijective XCD swizzle + col-major decode: each XCD owns 2 col-groups
    // (= one expert's full B panel) across all row-tiles.
    const int nwg = gridDim.x * gridDim.y;
    const int orig = blockIdx.y * gridDim.x + blockIdx.x;
    const int q = nwg >> 3, r8 = nwg & 7;
    const int xcd = orig & 7, idx = orig >> 3;
    const int wg = (xcd < r8 ? xcd * (q + 1) : r8 * (q + 1) + (xcd - r8) * q) + idx;
    const int group = wg / gridDim.y;          // 0..15 (2048 cols each)
    const long brow = (long)(wg % gridDim.y) * 256;

    const __bf16* Atile = A + brow * lda;
    __bf16* A0 = lds;
    __bf16* A1 = lds + 16384;
    __bf16* B0 = lds + 32768;
    __bf16* B1 = lds + 49152;

#define SA1(ss, bufp, hf) do { if ((ss) < 128) \
    stage_half(Atile, lda, bufp, hf, (long)((ss) & 15) << 6, t); } while (0)
#define SB1(ss, bufp, hf) do { if ((ss) < 128) \
    stage_half(Bt + ((size_t)(group * 8 + ((ss) >> 4))) * 256 * ldb, ldb, \
               bufp, hf, (long)((ss) & 15) << 6, t); } while (0)

    f32x4 acc[8][4];
#pragma unroll
    for (int m = 0; m < 8; ++m)
#pragma unroll
        for (int n = 0; n < 4; ++n) acc[m][n] = (f32x4)0.f;

    // prologue: A(0)->A0, B(0)->B0, B(1)->B1
    SA1(0, A0, 0); SA1(0, A0, 1);
    SB1(0, B0, 0); SB1(0, B0, 1);
    SB1(1, B1, 0); SB1(1, B1, 1);

    bf16x8 af[8], bq[8];
    for (int tile = 0; tile < 8; ++tile) {
        for (int itl = 0; itl < 8; ++itl) {
            const int it = (tile << 3) | itl;
            const int s0 = it << 1;
            const bool lastg = (it == 63);
            // P0
            SA1(s0 + 1, A1, 0);
            VMC6;
            BAR;
            RD_A(A0, 0);
            RD_B01(B0);
            WAIT_LGKM;
            QMFMA(0, 0);
            BAR;
            // P1
            RD_B23(B0);
            SA1(s0 + 1, A1, 1);
            BAR;
            WAIT_LGKM;
            QMFMA(0, 2);
            BAR;
            // P2
            RD_A(A0, 4);
            SB1(s0 + 2, B0, 0);
            BAR;
            WAIT_LGKM;
            QMFMA(4, 0);
            BAR;
            // P3
            SB1(s0 + 2, B0, 1);
            BAR;
            QMFMA(4, 2);
            BAR;
            // P4
            SA1(s0 + 2, A0, 0);
            if (lastg) { VMC0; } else { VMC6; }
            BAR;
            RD_A(A1, 0);
            RD_B01(B1);
            WAIT_LGKM;
            QMFMA(0, 0);
            BAR;
            // P5
            RD_B23(B1);
            SA1(s0 + 2, A0, 1);
            BAR;
            WAIT_LGKM;
            QMFMA(0, 2);
            BAR;
            // P6
            RD_A(A1, 4);
            SB1(s0 + 3, B1, 0);
            BAR;
            WAIT_LGKM;
            QMFMA(4, 0);
            BAR;
            // P7
            SB1(s0 + 3, B1, 1);
            BAR;
            QMFMA(4, 2);
            BAR;
        }
        // per-tile epilogue (no barriers; P0's BAR of next tile resyncs)
        {
            const long bcol = ((long)group * 8 + tile) * 256;
            const int ccol = (int)bcol + wc * 64 + (l & 15);
            const long crow0 = brow + wr * 128 + ((l >> 4) << 2);
            const int e = group >> 1;   // 16 tiles (4096 cols) per expert
            float bv[4];
#pragma unroll
            for (int n = 0; n < 4; ++n) bv[n] = bias[ccol + n * 16];
#pragma unroll
            for (int m = 0; m < 8; ++m)
#pragma unroll
                for (int j = 0; j < 4; ++j) {
                    long row = crow0 + m * 16 + j;
                    float g = gate[row * N_EXP + e];
                    size_t base = (size_t)row * NT + ccol;
#pragma unroll
                    for (int n = 0; n < 4; ++n)
                        outH[base + n * 16] =
                            (__bf16)(g * fmaxf(acc[m][n][j] + bv[n], 0.f));
                }
#pragma unroll
            for (int m = 0; m < 8; ++m)
#pragma unroll
                for (int n = 0; n < 4; ++n) acc[m][n] = (f32x4)0.f;
        }
    }
#undef SA1
#undef SB1
}

// ======= GEMM2: 256x256 / BK=64 / 8-wave / split-K partial (r8 form) =======
__global__ __launch_bounds__(512, 2)
void gemm2_p(const __bf16* __restrict__ A, long lda,
             const __bf16* __restrict__ Bt, long ldb,
             int nkt, float* __restrict__ outP, long zstride) {
    __shared__ __bf16 lds[65536];
    const int t = threadIdx.x;
    const int w = t >> 6, l = t & 63;
    const int wr = w >> 2, wc = w & 3;

    const int nwg = gridDim.x * gridDim.y;
    const int orig = blockIdx.y * gridDim.x + blockIdx.x;
    const int q = nwg >> 3, r8 = nwg & 7;
    const int xcd = orig & 7, idx = orig >> 3;
    const int wg = (xcd < r8 ? xcd * (q + 1) : r8 * (q + 1) + (xcd - r8) * q) + idx;
    const long bcol = (long)(wg / gridDim.y) * 256;
    const long brow = (long)(wg % gridDim.y) * 256;
    const long kbase = (long)blockIdx.z * KS;

    const __bf16* Atile = A + brow * lda + kbase;
    const __bf16* Btile = Bt + bcol * ldb + kbase;
    __bf16* A0 = lds;
    __bf16* A1 = lds + 16384;
    __bf16* B0 = lds + 32768;
    __bf16* B1 = lds + 49152;

    f32x4 acc[8][4];
#pragma unroll
    for (int m = 0; m < 8; ++m)
#pragma unroll
        for (int n = 0; n < 4; ++n) acc[m][n] = (f32x4)0.f;

    stage_half(Atile, lda, A0, 0, 0, t);
    stage_half(Atile, lda, A0, 1, 0, t);
    stage_half(Btile, ldb, B0, 0, 0, t);
    stage_half(Btile, ldb, B0, 1, 0, t);
    stage_half(Btile, ldb, B1, 0, 64, t);
    stage_half(Btile, ldb, B1, 1, 64, t);

    bf16x8 af[8], bq[8];
    const int niter = nkt >> 1;
    for (int it = 0; it < niter; ++it) {
        const long kb = (long)it * 128;
        const bool nl = (it < niter - 1);
        stage_half(Atile, lda, A1, 0, kb + 64, t);
        VMC6;
        BAR;
        RD_A(A0, 0);
        RD_B01(B0);
        WAIT_LGKM;
        QMFMA(0, 0);
        BAR;
        RD_B23(B0);
        stage_half(Atile, lda, A1, 1, kb + 64, t);
        BAR;
        WAIT_LGKM;
        QMFMA(0, 2);
        BAR;
        RD_A(A0, 4);
        if (nl) stage_half(Btile, ldb, B0, 0, kb + 128, t);
        BAR;
        WAIT_LGKM;
        QMFMA(4, 0);
        BAR;
        if (nl) stage_half(Btile, ldb, B0, 1, kb + 128, t);
        BAR;
        QMFMA(4, 2);
        BAR;
        if (nl) {
            stage_half(Atile, lda, A0, 0, kb + 128, t);
            VMC6;
        } else {
            VMC0;
        }
        BAR;
        RD_A(A1, 0);
        RD_B01(B1);
        WAIT_LGKM;
        QMFMA(0, 0);
        BAR;
        RD_B23(B1);
        if (nl) stage_half(Atile, lda, A0, 1, kb + 128, t);
        BAR;
        WAIT_LGKM;
        QMFMA(0, 2);
        BAR;
        RD_A(A1, 4);
        if (nl) stage_half(Btile, ldb, B1, 0, kb + 192, t);
        BAR;
        WAIT_LGKM;
        QMFMA(4, 0);
        BAR;
        if (nl) stage_half(Btile, ldb, B1, 1, kb + 192, t);
        BAR;
        QMFMA(4, 2);
        BAR;
    }

    const int ccol = (int)bcol + wc * 64 + (l & 15);
    const long crow0 = brow + wr * 128 + ((l >> 4) << 2);
    float* op = outP + (size_t)blockIdx.z * zstride;
#pragma unroll
    for (int m = 0; m < 8; ++m)
#pragma unroll
        for (int j = 0; j < 4; ++j) {
            long row = crow0 + m * 16 + j;
            size_t base = (size_t)row * D_OUT + ccol;
#pragma unroll
            for (int n = 0; n < 4; ++n)
                op[base + n * 16] = acc[m][n][j];
        }
}

// ---- reduce: out = sum_ks partial + sum_e gate_e * b2_e  (float4/thread) --
__global__ void reduce_kernel(const float* __restrict__ partial,
                              const float* __restrict__ gate,
                              const float* __restrict__ b2,
                              float* __restrict__ out, int rows) {
    int idx = blockIdx.x * 256 + threadIdx.x;
    if (idx >= rows * 256) return;
    int r = idx >> 8;
    int c = (idx & 255) * 4;
    size_t zstride = (size_t)rows * D_OUT;
    f32x4 s = (f32x4)0.f;
#pragma unroll
    for (int ks = 0; ks < SPLITK; ++ks)
        s += *(const f32x4*)&partial[ks * zstride + (size_t)r * D_OUT + c];
#pragma unroll
    for (int e = 0; e < N_EXP; ++e) {
        float g = gate[(size_t)r * N_EXP + e];
        f32x4 bv = *(const f32x4*)&b2[(size_t)e * D_OUT + c];
        s += g * bv;
    }
    *(f32x4*)&out[(size_t)r * D_OUT + c] = s;
}

// ---------------------------------------------------------------------------
extern "C" void kernel_launch(void* const* d_in, const int* in_sizes, int n_in,
                              void* d_out, int out_size, void* d_ws, size_t ws_size,
                              hipStream_t stream) {
    const float* x  = (const float*)d_in[0];
    const float* W1 = (const float*)d_in[1];
    const float* b1 = (const float*)d_in[2];
    const float* W2 = (const float*)d_in[3];
    const float* b2 = (const float*)d_in[4];
    const float* Wg = (const float*)d_in[5];
    const float* bg = (const float*)d_in[6];
    float* out = (float*)d_out;

    char* ws = (char*)d_ws;
    size_t off = 0;
    auto take = [&](size_t bytes) {
        char* p = ws + off;
        off = (off + bytes + 255) & ~(size_t)255;
        return p;
    };
    float*  gate = (float*)take((size_t)B_TOK * N_EXP * 4);
    __bf16* xb   = (__bf16*)take((size_t)B_TOK * DD_IN * 2);
    __bf16* W1t  = (__bf16*)take((size_t)NT * DD_IN * 2);   // [NT][DD_IN]
    __bf16* W2tt = (__bf16*)take((size_t)D_OUT * NT * 2);   // [D_OUT][NT]
    size_t remain = (ws_size > off) ? (ws_size - off) : 0;
    size_t per_row = (size_t)NT * 2 + (size_t)SPLITK * D_OUT * 4;
    long Rc = (long)(remain / per_row);
    Rc &= ~255L;
    // Rc=4096 (round-8 best): GEMM2 grid 4x16x4 = 256 blocks = 1 exact round;
    // GEMM1 persistent grid 16x16 = 256 blocks, 8 tiles each.
    if (Rc > 4096) Rc = 4096;
    if (Rc < 256) Rc = 256;
    __bf16* h       = (__bf16*)take((size_t)Rc * NT * 2);
    float*  partial = (float*)(ws + off);

    gate_cvt_kernel<<<dim3(B_TOK / 4), dim3(256), 0, stream>>>(x, Wg, bg, gate, xb);

    transpose_cvt64<<<dim3(D_HID / 64, DD_IN / 64, N_EXP), dim3(256), 0, stream>>>(
        W1, W1t, DD_IN, D_HID, DD_IN, (long)D_HID * DD_IN);
    transpose_cvt64<<<dim3(D_OUT / 64, D_HID / 64, N_EXP), dim3(256), 0, stream>>>(
        W2, W2tt, D_HID, D_OUT, NT, D_HID);

    for (long r0 = 0; r0 < B_TOK; r0 += Rc) {
        long rows = B_TOK - r0;
        if (rows > Rc) rows = Rc;
        gemm1p<<<dim3(NT / 2048, rows / 256), dim3(512), 0, stream>>>(
            xb + (size_t)r0 * DD_IN, DD_IN, W1t, DD_IN,
            b1, gate + (size_t)r0 * N_EXP, h);
        gemm2_p<<<dim3(D_OUT / 256, rows / 256, SPLITK), dim3(512), 0, stream>>>(
            h, NT, W2tt, NT, KS / 64, partial, (long)rows * D_OUT);
        reduce_kernel<<<dim3((int)rows, 1, 1), dim3(256), 0, stream>>>(
            partial, gate + (size_t)r0 * N_EXP, b2, out + (size_t)r0 * D_OUT,
            (int)rows);
    }
}

// Round 16
// 1146.922 us; speedup vs baseline: 1.1421x; 1.1421x over previous
//
#include <hip/hip_runtime.h>
#include <hip/hip_bf16.h>
#include <stdint.h>

#define B_TOK 8192
#define DD_IN 1024
#define D_HID 4096
#define D_OUT 1024
#define N_EXP 8
#define NT    (N_EXP * D_HID)   // 32768: fused hidden width = GEMM2 K
#define SPLITK 4
#define KS    (NT / SPLITK)     // 8192 k per split block

typedef __attribute__((ext_vector_type(8))) __bf16 bf16x8;
typedef __attribute__((ext_vector_type(4))) float f32x4;

// ------ fused gate+cvt: gate = softmax(x@Wg+bg); xb = bf16(x). 1 wave/row --
__global__ void gate_cvt_kernel(const float* __restrict__ x,
                                const float* __restrict__ Wg,
                                const float* __restrict__ bg,
                                float* __restrict__ gate,
                                __bf16* __restrict__ xb) {
    int wave = threadIdx.x >> 6;
    int lane = threadIdx.x & 63;
    int row  = blockIdx.x * 4 + wave;
    if (row >= B_TOK) return;
    const float* xr = x + (size_t)row * DD_IN;
    __bf16* xbr = xb + (size_t)row * DD_IN;
    float acc[N_EXP];
#pragma unroll
    for (int e = 0; e < N_EXP; ++e) acc[e] = 0.f;
#pragma unroll
    for (int c = 0; c < 4; ++c) {
        int k = (c * 64 + lane) * 4;
        float4 v = *(const float4*)&xr[k];
        __bf16 b0 = (__bf16)v.x, b1 = (__bf16)v.y, b2 = (__bf16)v.z, b3 = (__bf16)v.w;
        ushort4 u;
        u.x = *(unsigned short*)&b0; u.y = *(unsigned short*)&b1;
        u.z = *(unsigned short*)&b2; u.w = *(unsigned short*)&b3;
        *(ushort4*)&xbr[k] = u;
        const float* wg0 = Wg + (size_t)k * N_EXP;
#pragma unroll
        for (int e = 0; e < N_EXP; ++e)
            acc[e] += v.x * wg0[e] + v.y * wg0[N_EXP + e] +
                      v.z * wg0[2 * N_EXP + e] + v.w * wg0[3 * N_EXP + e];
    }
#pragma unroll
    for (int e = 0; e < N_EXP; ++e) {
        float v = acc[e];
        for (int off = 32; off; off >>= 1) v += __shfl_xor(v, off);
        acc[e] = v + bg[e];
    }
    float m = acc[0];
#pragma unroll
    for (int e = 1; e < N_EXP; ++e) m = fmaxf(m, acc[e]);
    float s = 0.f;
#pragma unroll
    for (int e = 0; e < N_EXP; ++e) { acc[e] = expf(acc[e] - m); s += acc[e]; }
    float inv = 1.f / s;
    if (lane < N_EXP) gate[(size_t)row * N_EXP + lane] = acc[lane] * inv;
}

// ---- wide transpose+convert: out[c*ldo + e*eStride + r] = bf16(in[e][r][c])
__global__ __launch_bounds__(256)
void transpose_cvt64(const float* __restrict__ in,
                     __bf16* __restrict__ out, int R, int C,
                     long ldo, long eStride) {
    __shared__ __bf16 tile[64 * 66];
    const float* inp = in + (size_t)blockIdx.z * R * C;
    __bf16* outp = out + (size_t)blockIdx.z * eStride;
    const int c0 = blockIdx.x * 64, r0 = blockIdx.y * 64;
    const int t = threadIdx.x;
    const int lr = t >> 4;
    const int lc = (t & 15) * 4;
#pragma unroll
    for (int p = 0; p < 4; ++p) {
        int r = p * 16 + lr;
        float4 v = *(const float4*)&inp[(size_t)(r0 + r) * C + c0 + lc];
        ushort2 u01, u23;
        __bf16 b0 = (__bf16)v.x, b1 = (__bf16)v.y, b2 = (__bf16)v.z, b3 = (__bf16)v.w;
        u01.x = *(unsigned short*)&b0; u01.y = *(unsigned short*)&b1;
        u23.x = *(unsigned short*)&b2; u23.y = *(unsigned short*)&b3;
        *(ushort2*)&tile[r * 66 + lc]     = u01;
        *(ushort2*)&tile[r * 66 + lc + 2] = u23;
    }
    __syncthreads();
#pragma unroll
    for (int p = 0; p < 2; ++p) {
        int item = p * 256 + t;
        int cc = item >> 3;
        int rb = (item & 7) * 8;
        bf16x8 v;
#pragma unroll
        for (int k = 0; k < 8; ++k) v[k] = tile[(rb + k) * 66 + cc];
        *(bf16x8*)&outp[(size_t)(c0 + cc) * ldo + r0 + rb] = v;
    }
}

// ================= 256x256 / BK=64 / 8-wave / 8-phase GEMM =================
__device__ __forceinline__ void stage_half(const __bf16* __restrict__ gsrc, long ld,
                                           __bf16* ldsbase, int hf, long k0, int t) {
#pragma unroll
    for (int i = 0; i < 2; ++i) {
        int g = i * 512 + t;
        int rl = g >> 3, sl = g & 7;
        int r = hf * 128 + rl;
        const __bf16* src = gsrc + (size_t)r * ld + k0 + ((sl ^ (r & 7)) << 3);
        __builtin_amdgcn_global_load_lds(
            (const __attribute__((address_space(1))) void*)src,
            (__attribute__((address_space(3))) void*)(ldsbase + hf * 8192 + g * 8),
            16, 0, 0);
    }
}

__device__ __forceinline__ bf16x8 ldfrag(const __bf16* buf, int rbase, int l, int ks) {
    int r = rbase + (l & 15);
    int k = ks * 32 + ((l >> 4) << 3);
    return *(const bf16x8*)(buf + r * 64 + (k ^ ((r & 7) << 3)));
}

#define WAIT_LGKM do { asm volatile("s_waitcnt lgkmcnt(0)" ::: "memory"); \
    __builtin_amdgcn_sched_barrier(0); } while (0)
#define BAR __builtin_amdgcn_s_barrier()

#define RD_A(bufp, mb) do { \
    _Pragma("unroll") for (int mm = 0; mm < 4; ++mm) \
    _Pragma("unroll") for (int ks = 0; ks < 2; ++ks) \
        af[mm * 2 + ks] = ldfrag((bufp), wr * 128 + ((mb) + mm) * 16, l, ks); \
} while (0)
#define RD_B01(bufp) do { \
    _Pragma("unroll") for (int nn = 0; nn < 2; ++nn) \
    _Pragma("unroll") for (int ks = 0; ks < 2; ++ks) \
        bq[nn * 2 + ks] = ldfrag((bufp), wc * 64 + nn * 16, l, ks); \
} while (0)
#define RD_B23(bufp) do { \
    _Pragma("unroll") for (int nn = 2; nn < 4; ++nn) \
    _Pragma("unroll") for (int ks = 0; ks < 2; ++ks) \
        bq[nn * 2 + ks] = ldfrag((bufp), wc * 64 + nn * 16, l, ks); \
} while (0)
#define QMFMA(mb, nb) do { \
    __builtin_amdgcn_s_setprio(1); \
    _Pragma("unroll") for (int mm = 0; mm < 4; ++mm) \
    _Pragma("unroll") for (int nn = 0; nn < 2; ++nn) \
    _Pragma("unroll") for (int ks = 0; ks < 2; ++ks) \
        acc[(mb) + mm][(nb) + nn] = __builtin_amdgcn_mfma_f32_16x16x32_bf16( \
            af[mm * 2 + ks], bq[((nb) + nn) * 2 + ks], acc[(mb) + mm][(nb) + nn], 0, 0, 0); \
    __builtin_amdgcn_s_setprio(0); \
} while (0)

template <int EPI>
__global__ __launch_bounds__(512, 2)
void gemm8p(const __bf16* __restrict__ A, long lda,
            const __bf16* __restrict__ Bt, long ldb,
            int nkt, const float* __restrict__ bias,
            const float* __restrict__ gate,
            __bf16* __restrict__ outH, float* __restrict__ outP,
            long zstride) {
    __shared__ __bf16 lds[65536];
    const int t = threadIdx.x;
    const int w = t >> 6, l = t & 63;
    const int wr = w >> 2, wc = w & 3;

    const int nwg = gridDim.x * gridDim.y;
    const int orig = blockIdx.y * gridDim.x + blockIdx.x;
    const int q = nwg >> 3, r8 = nwg & 7;
    const int xcd = orig & 7, idx = orig >> 3;
    const int wg = (xcd < r8 ? xcd * (q + 1) : r8 * (q + 1) + (xcd - r8) * q) + idx;
    const long brow = (long)(wg / gridDim.x) * 256;
    const long bcol = (long)(wg % gridDim.x) * 256;
    const long kbase = (EPI == 1) ? (long)blockIdx.z * KS : 0;

    const __bf16* Atile = A + brow * lda + kbase;
    const __bf16* Btile = Bt + bcol * ldb + kbase;
    __bf16* A0 = lds;
    __bf16* A1 = lds + 16384;
    __bf16* B0 = lds + 32768;
    __bf16* B1 = lds + 49152;

    f32x4 acc[8][4];
#pragma unroll
    for (int m = 0; m < 8; ++m)
#pragma unroll
        for (int n = 0; n < 4; ++n) acc[m][n] = (f32x4)0.f;

    stage_half(Atile, lda, A0, 0, 0, t);
    stage_half(Atile, lda, A0, 1, 0, t);
    stage_half(Btile, ldb, B0, 0, 0, t);
    stage_half(Btile, ldb, B0, 1, 0, t);
    stage_half(Btile, ldb, B1, 0, 64, t);
    stage_half(Btile, ldb, B1, 1, 64, t);

    bf16x8 af[8], bq[8];
    const int niter = nkt >> 1;
    for (int it = 0; it < niter; ++it) {
        const long kb = (long)it * 128;
        const bool nl = (it < niter - 1);
        stage_half(Atile, lda, A1, 0, kb + 64, t);
        asm volatile("s_waitcnt vmcnt(6)" ::: "memory");
        __builtin_amdgcn_sched_barrier(0);
        BAR;
        RD_A(A0, 0);
        RD_B01(B0);
        WAIT_LGKM;
        QMFMA(0, 0);
        BAR;
        RD_B23(B0);
        stage_half(Atile, lda, A1, 1, kb + 64, t);
        BAR;
        WAIT_LGKM;
        QMFMA(0, 2);
        BAR;
        RD_A(A0, 4);
        if (nl) stage_half(Btile, ldb, B0, 0, kb + 128, t);
        BAR;
        WAIT_LGKM;
        QMFMA(4, 0);
        BAR;
        if (nl) stage_half(Btile, ldb, B0, 1, kb + 128, t);
        BAR;
        QMFMA(4, 2);
        BAR;
        if (nl) {
            stage_half(Atile, lda, A0, 0, kb + 128, t);
            asm volatile("s_waitcnt vmcnt(6)" ::: "memory");
        } else {
            asm volatile("s_waitcnt vmcnt(0)" ::: "memory");
        }
        __builtin_amdgcn_sched_barrier(0);
        BAR;
        RD_A(A1, 0);
        RD_B01(B1);
        WAIT_LGKM;
        QMFMA(0, 0);
        BAR;
        RD_B23(B1);
        if (nl) stage_half(Atile, lda, A0, 1, kb + 128, t);
        BAR;
        WAIT_LGKM;
        QMFMA(0, 2);
        BAR;
        RD_A(A1, 4);
        if (nl) stage_half(Btile, ldb, B1, 0, kb + 192, t);
        BAR;
        WAIT_LGKM;
        QMFMA(4, 0);
        BAR;
        if (nl) stage_half(Btile, ldb, B1, 1, kb + 192, t);
        BAR;
        QMFMA(4, 2);
        BAR;
    }

    const int ccol = (int)bcol + wc * 64 + (l & 15);
    const long crow0 = brow + wr * 128 + ((l >> 4) << 2);
    if (EPI == 0) {
        const int e = (int)(bcol >> 12);
        float bv[4];
#pragma unroll
        for (int n = 0; n < 4; ++n) bv[n] = bias[ccol + n * 16];
#pragma unroll
        for (int m = 0; m < 8; ++m)
#pragma unroll
            for (int j = 0; j < 4; ++j) {
                long row = crow0 + m * 16 + j;
                float g = gate[row * N_EXP + e];
                size_t base = (size_t)row * NT + ccol;
#pragma unroll
                for (int n = 0; n < 4; ++n)
                    outH[base + n * 16] =
                        (__bf16)(g * fmaxf(acc[m][n][j] + bv[n], 0.f));
            }
    } else {
        float* op = outP + (size_t)blockIdx.z * zstride;
#pragma unroll
        for (int m = 0; m < 8; ++m)
#pragma unroll
            for (int j = 0; j < 4; ++j) {
                long row = crow0 + m * 16 + j;
                size_t base = (size_t)row * D_OUT + ccol;
#pragma unroll
                for (int n = 0; n < 4; ++n)
                    op[base + n * 16] = acc[m][n][j];
            }
    }
}

// ---- reduce: out = sum_ks partial + sum_e gate_e * b2_e  (float4/thread) --
__global__ void reduce_kernel(const float* __restrict__ partial,
                              const float* __restrict__ gate,
                              const float* __restrict__ b2,
                              float* __restrict__ out, int rows) {
    int idx = blockIdx.x * 256 + threadIdx.x;
    if (idx >= rows * 256) return;
    int r = idx >> 8;
    int c = (idx & 255) * 4;
    size_t zstride = (size_t)rows * D_OUT;
    f32x4 s = (f32x4)0.f;
#pragma unroll
    for (int ks = 0; ks < SPLITK; ++ks)
        s += *(const f32x4*)&partial[ks * zstride + (size_t)r * D_OUT + c];
#pragma unroll
    for (int e = 0; e < N_EXP; ++e) {
        float g = gate[(size_t)r * N_EXP + e];
        f32x4 bv = *(const f32x4*)&b2[(size_t)e * D_OUT + c];
        s += g * bv;
    }
    *(f32x4*)&out[(size_t)r * D_OUT + c] = s;
}

// ---------------------------------------------------------------------------
extern "C" void kernel_launch(void* const* d_in, const int* in_sizes, int n_in,
                              void* d_out, int out_size, void* d_ws, size_t ws_size,
                              hipStream_t stream) {
    const float* x  = (const float*)d_in[0];
    const float* W1 = (const float*)d_in[1];
    const float* b1 = (const float*)d_in[2];
    const float* W2 = (const float*)d_in[3];
    const float* b2 = (const float*)d_in[4];
    const float* Wg = (const float*)d_in[5];
    const float* bg = (const float*)d_in[6];
    float* out = (float*)d_out;

    char* ws = (char*)d_ws;
    size_t off = 0;
    auto take = [&](size_t bytes) {
        char* p = ws + off;
        off = (off + bytes + 255) & ~(size_t)255;
        return p;
    };
    float*  gate = (float*)take((size_t)B_TOK * N_EXP * 4);
    __bf16* xb   = (__bf16*)take((size_t)B_TOK * DD_IN * 2);
    __bf16* W1t  = (__bf16*)take((size_t)NT * DD_IN * 2);   // [NT][DD_IN]
    __bf16* W2tt = (__bf16*)take((size_t)D_OUT * NT * 2);   // [D_OUT][NT]
    size_t remain = (ws_size > off) ? (ws_size - off) : 0;
    size_t per_row = (size_t)NT * 2 + (size_t)SPLITK * D_OUT * 4;
    long Rc = (long)(remain / per_row);
    Rc &= ~255L;
    // Cap at 4096 (round-8 best): GEMM2 grid = 4 x 16 x 4 = 256 blocks =
    // exactly one full-occupancy round; GEMM1 grid = 128 x 16 = 8 exact
    // rounds. Rc=4352 gave 272 blocks -> ~200us straggler tail (r7 lesson).
    if (Rc > 4096) Rc = 4096;
    if (Rc < 256) Rc = 256;
    __bf16* h       = (__bf16*)take((size_t)Rc * NT * 2);
    float*  partial = (float*)(ws + off);

    gate_cvt_kernel<<<dim3(B_TOK / 4), dim3(256), 0, stream>>>(x, Wg, bg, gate, xb);

    transpose_cvt64<<<dim3(D_HID / 64, DD_IN / 64, N_EXP), dim3(256), 0, stream>>>(
        W1, W1t, DD_IN, D_HID, DD_IN, (long)D_HID * DD_IN);
    transpose_cvt64<<<dim3(D_OUT / 64, D_HID / 64, N_EXP), dim3(256), 0, stream>>>(
        W2, W2tt, D_HID, D_OUT, NT, D_HID);

    for (long r0 = 0; r0 < B_TOK; r0 += Rc) {
        long rows = B_TOK - r0;
        if (rows > Rc) rows = Rc;
        gemm8p<0><<<dim3(NT / 256, rows / 256), dim3(512), 0, stream>>>(
            xb + (size_t)r0 * DD_IN, DD_IN, W1t, DD_IN, DD_IN / 64,
            b1, gate + (size_t)r0 * N_EXP, h, nullptr, 0);
        gemm8p<1><<<dim3(D_OUT / 256, rows / 256, SPLITK), dim3(512), 0, stream>>>(
            h, NT, W2tt, NT, KS / 64,
            nullptr, nullptr, nullptr, partial, (long)rows * D_OUT);
        reduce_kernel<<<dim3((int)rows, 1, 1), dim3(256), 0, stream>>>(
            partial, gate + (size_t)r0 * N_EXP, b2, out + (size_t)r0 * D_OUT,
            (int)rows);
    }
}